// Round 1
// baseline (24623.105 us; speedup 1.0000x reference)
//
#include <hip/hip_runtime.h>
#include <cstdint>
#include <cstddef>

#define BN_EPS 1e-5f

__device__ __forceinline__ float sigf(float x) {
    return 1.0f / (1.0f + __expf(-x));
}
__device__ __forceinline__ float tanhfast(float x) {
    return 2.0f / (1.0f + __expf(-2.0f * x)) - 1.0f;
}
__device__ __forceinline__ unsigned bfr(float x) {  // f32 -> bf16 bits (RNE)
    unsigned u = __float_as_uint(x);
    return (u + 0x7fffu + ((u >> 16) & 1u)) >> 16;
}

// ---------------- conv1 + BN + ReLU : x[B,T,9] -> y1[B,32,T] ----------------
__global__ __launch_bounds__(256) void k_conv1(
    const float* __restrict__ x, const float* __restrict__ w,
    const float* __restrict__ g, const float* __restrict__ bb,
    const float* __restrict__ m, const float* __restrict__ v,
    float* __restrict__ y1, int B, int T)
{
    const int TT = 256;
    __shared__ float xs[(TT + 6) * 9];
    const int b = blockIdx.y;
    const int t0 = blockIdx.x * TT;
    const int tid = threadIdx.x;

    for (int idx = tid; idx < (TT + 6) * 9; idx += 256) {
        int row = idx / 9, col = idx - row * 9;
        int tg = t0 - 3 + row;
        xs[idx] = (tg >= 0 && tg < T) ? x[((size_t)b * T + tg) * 9 + col] : 0.0f;
    }
    __syncthreads();

    float xv[63];
#pragma unroll
    for (int k = 0; k < 7; ++k)
#pragma unroll
        for (int ci = 0; ci < 9; ++ci)
            xv[k * 9 + ci] = xs[(tid + k) * 9 + ci];

    const int t = t0 + tid;
    for (int co = 0; co < 32; ++co) {
        float acc = 0.0f;
#pragma unroll
        for (int ci = 0; ci < 9; ++ci)
#pragma unroll
            for (int k = 0; k < 7; ++k)
                acc += xv[k * 9 + ci] * w[(co * 9 + ci) * 7 + k];
        float sc = g[co] / sqrtf(v[co] + BN_EPS);
        float bf = bb[co] - m[co] * sc;
        float o = acc * sc + bf;
        y1[((size_t)b * 32 + co) * T + t] = o > 0.0f ? o : 0.0f;
    }
}

// ---------------- conv2 + BN + ReLU : y1[B,32,T] -> y2[B,64,T] --------------
__global__ __launch_bounds__(256) void k_conv2(
    const float* __restrict__ y1, const float* __restrict__ w,
    const float* __restrict__ g, const float* __restrict__ bb,
    const float* __restrict__ m, const float* __restrict__ v,
    float* __restrict__ y2, int B, int T)
{
    const int TT = 256;
    __shared__ float ys[32 * (TT + 6)];
    const int b = blockIdx.y;
    const int t0 = blockIdx.x * TT;
    const int tid = threadIdx.x;

    for (int idx = tid; idx < 32 * (TT + 6); idx += 256) {
        int ci = idx / (TT + 6), i = idx - ci * (TT + 6);
        int tg = t0 - 3 + i;
        ys[idx] = (tg >= 0 && tg < T) ? y1[((size_t)b * 32 + ci) * T + tg] : 0.0f;
    }
    __syncthreads();

    float acc[64];
#pragma unroll
    for (int co = 0; co < 64; ++co) acc[co] = 0.0f;

    for (int ci = 0; ci < 32; ++ci) {
        float yw[7];
#pragma unroll
        for (int k = 0; k < 7; ++k) yw[k] = ys[ci * (TT + 6) + tid + k];
#pragma unroll
        for (int co = 0; co < 64; ++co)
#pragma unroll
            for (int k = 0; k < 7; ++k)
                acc[co] += yw[k] * w[(co * 32 + ci) * 7 + k];
    }

    const int t = t0 + tid;
    for (int co = 0; co < 64; ++co) {
        float sc = g[co] / sqrtf(v[co] + BN_EPS);
        float bf = bb[co] - m[co] * sc;
        float o = acc[co] * sc + bf;
        y2[((size_t)b * 64 + co) * T + t] = o > 0.0f ? o : 0.0f;
    }
}

// ------------- conv3 + BN + ReLU : y2[B,64,T] -> feat[B,T,128] --------------
__global__ __launch_bounds__(256) void k_conv3(
    const float* __restrict__ y2, const float* __restrict__ w,
    const float* __restrict__ g, const float* __restrict__ bb,
    const float* __restrict__ m, const float* __restrict__ v,
    float* __restrict__ feat, int B, int T)
{
    const int TT = 128;
    __shared__ float ys[64 * (TT + 6)];
    const int b = blockIdx.y;
    const int t0 = blockIdx.x * TT;
    const int tid = threadIdx.x;
    const int tl = tid & 127;
    const int half = __builtin_amdgcn_readfirstlane(tid >> 7);  // wave-uniform

    for (int idx = tid; idx < 64 * (TT + 6); idx += 256) {
        int ci = idx / (TT + 6), i = idx - ci * (TT + 6);
        int tg = t0 - 3 + i;
        ys[idx] = (tg >= 0 && tg < T) ? y2[((size_t)b * 64 + ci) * T + tg] : 0.0f;
    }
    __syncthreads();

    float acc[64];
#pragma unroll
    for (int q = 0; q < 64; ++q) acc[q] = 0.0f;

    for (int ci = 0; ci < 64; ++ci) {
        float yw[7];
#pragma unroll
        for (int k = 0; k < 7; ++k) yw[k] = ys[ci * (TT + 6) + tl + k];
#pragma unroll
        for (int q = 0; q < 64; ++q)
#pragma unroll
            for (int k = 0; k < 7; ++k)
                acc[q] += yw[k] * w[((half * 64 + q) * 64 + ci) * 7 + k];
    }

    const int t = t0 + tl;
    for (int q = 0; q < 64; ++q) {
        int co = half * 64 + q;
        float sc = g[co] / sqrtf(v[co] + BN_EPS);
        float bf = bb[co] - m[co] * sc;
        float o = acc[q] * sc + bf;
        feat[((size_t)b * T + t) * 128 + co] = o > 0.0f ? o : 0.0f;
    }
}

// ------- input projection: xpre[r,512] = feat[r,:]@w_ih^T + b_ih + b_hh -----
__global__ __launch_bounds__(256) void k_proj(
    const float* __restrict__ feat, const float* __restrict__ w_ih,
    const float* __restrict__ b_ih, const float* __restrict__ b_hh,
    float* __restrict__ xpre)
{
    __shared__ float fs[64 * 129];
    const int row0 = blockIdx.x * 64;
    const int tid = threadIdx.x;
    const int tl = tid & 63;
    const int jq = __builtin_amdgcn_readfirstlane(tid >> 6);  // wave-uniform
    const int jb = blockIdx.y * 128 + jq * 32;

    for (int idx = tid; idx < 64 * 128; idx += 256) {
        int r = idx >> 7, c = idx & 127;
        fs[r * 129 + c] = feat[((size_t)row0 + r) * 128 + c];
    }
    __syncthreads();

    float acc[32];
#pragma unroll
    for (int jj = 0; jj < 32; ++jj) acc[jj] = b_ih[jb + jj] + b_hh[jb + jj];

    for (int k4 = 0; k4 < 32; ++k4) {
        float f0 = fs[tl * 129 + k4 * 4 + 0];
        float f1 = fs[tl * 129 + k4 * 4 + 1];
        float f2 = fs[tl * 129 + k4 * 4 + 2];
        float f3 = fs[tl * 129 + k4 * 4 + 3];
#pragma unroll
        for (int jj = 0; jj < 32; ++jj) {
            const float* wr = &w_ih[(size_t)(jb + jj) * 128 + k4 * 4];
            acc[jj] += f0 * wr[0] + f1 * wr[1] + f2 * wr[2] + f3 * wr[3];
        }
    }

    const size_t orow = ((size_t)row0 + tl) * 512 + jb;
#pragma unroll
    for (int jj = 0; jj < 32; jj += 4) {
        float4 vv = make_float4(acc[jj], acc[jj + 1], acc[jj + 2], acc[jj + 3]);
        *reinterpret_cast<float4*>(&xpre[orow + jj]) = vv;
    }
}

// --------------------------- reversed-time LSTM -----------------------------
// ONFLY=false: src = xpre[B*T,512] (proj+biases baked in)
// ONFLY=true : src = feat[B*T,128]; w_ih applied on the fly (bf16 in regs)
template <bool ONFLY>
__global__ __launch_bounds__(512, 2) void k_lstm(
    const float* __restrict__ src, const float* __restrict__ w_hh,
    const float* __restrict__ w_ih, const float* __restrict__ b_ih,
    const float* __restrict__ b_hh, float* __restrict__ out, int T)
{
    __shared__ __align__(16) float h_sh[128];
    __shared__ __align__(16) float x_sh[128];
    __shared__ float g_sh[512];

    const int b = blockIdx.x;
    const int j = threadIdx.x;

    float4 wh[32];
    const float4* whp = reinterpret_cast<const float4*>(w_hh + (size_t)j * 128);
#pragma unroll
    for (int k4 = 0; k4 < 32; ++k4) wh[k4] = whp[k4];

    unsigned wiu[64];
    float bias = 0.0f;
    if (ONFLY) {
#pragma unroll
        for (int k2 = 0; k2 < 64; ++k2) {
            float a = w_ih[(size_t)j * 128 + 2 * k2];
            float c = w_ih[(size_t)j * 128 + 2 * k2 + 1];
            wiu[k2] = (bfr(c) << 16) | bfr(a);
        }
        bias = b_ih[j] + b_hh[j];
    }

    float cst = 0.0f;
    if (j < 128) h_sh[j] = 0.0f;

    float xv;
    if (ONFLY)
        xv = (j < 128) ? src[((size_t)b * T + (T - 1)) * 128 + j] : 0.0f;
    else
        xv = src[((size_t)b * T + (T - 1)) * 512 + j];

    for (int t = T - 1; t >= 0; --t) {
        if (ONFLY && j < 128) x_sh[j] = xv;
        float xv_n = 0.0f;
        if (t > 0) {
            if (ONFLY) {
                if (j < 128) xv_n = src[((size_t)b * T + (t - 1)) * 128 + j];
            } else {
                xv_n = src[((size_t)b * T + (t - 1)) * 512 + j];
            }
        }
        __syncthreads();  // A: h_sh (and x_sh) ready, g_sh free

        float a0 = ONFLY ? bias : xv, a1 = 0.0f, a2 = 0.0f, a3 = 0.0f;
        const float4* hv = reinterpret_cast<const float4*>(h_sh);
        const float4* xvv = reinterpret_cast<const float4*>(x_sh);
#pragma unroll
        for (int k4 = 0; k4 < 32; ++k4) {
            float4 h4 = hv[k4];
            float4 w4 = wh[k4];
            a0 += h4.x * w4.x;
            a1 += h4.y * w4.y;
            a2 += h4.z * w4.z;
            a3 += h4.w * w4.w;
            if (ONFLY) {
                float4 x4 = xvv[k4];
                unsigned u0 = wiu[2 * k4], u1 = wiu[2 * k4 + 1];
                a0 += x4.x * __uint_as_float(u0 << 16);
                a1 += x4.y * __uint_as_float(u0 & 0xffff0000u);
                a2 += x4.z * __uint_as_float(u1 << 16);
                a3 += x4.w * __uint_as_float(u1 & 0xffff0000u);
            }
        }
        g_sh[j] = (a0 + a1) + (a2 + a3);
        __syncthreads();  // B: gates ready

        if (j < 128) {
            float ig = sigf(g_sh[j]);
            float fg = sigf(g_sh[j + 128]);
            float gg = tanhfast(g_sh[j + 256]);
            float og = sigf(g_sh[j + 384]);
            cst = fg * cst + ig * gg;
            float h = og * tanhfast(cst);
            h_sh[j] = h;
            out[((size_t)b * T + t) * 128 + j] = h;
        }
        xv = xv_n;
    }
}

extern "C" void kernel_launch(void* const* d_in, const int* in_sizes, int n_in,
                              void* d_out, int out_size, void* d_ws, size_t ws_size,
                              hipStream_t stream)
{
    const float* x    = (const float*)d_in[0];
    const float* c1w  = (const float*)d_in[1];
    const float* bn1g = (const float*)d_in[2];
    const float* bn1b = (const float*)d_in[3];
    const float* bn1m = (const float*)d_in[4];
    const float* bn1v = (const float*)d_in[5];
    const float* c2w  = (const float*)d_in[6];
    const float* bn2g = (const float*)d_in[7];
    const float* bn2b = (const float*)d_in[8];
    const float* bn2m = (const float*)d_in[9];
    const float* bn2v = (const float*)d_in[10];
    const float* c3w  = (const float*)d_in[11];
    const float* bn3g = (const float*)d_in[12];
    const float* bn3b = (const float*)d_in[13];
    const float* bn3m = (const float*)d_in[14];
    const float* bn3v = (const float*)d_in[15];
    const float* w_ih = (const float*)d_in[16];
    const float* w_hh = (const float*)d_in[17];
    const float* b_ih = (const float*)d_in[18];
    const float* b_hh = (const float*)d_in[19];
    float* out = (float*)d_out;

    const int B = 64, T = 4096;
    char* ws = (char*)d_ws;
    const size_t sz_y1   = (size_t)B * 32 * T * 4;   //  32 MB
    const size_t sz_y2   = (size_t)B * 64 * T * 4;   //  64 MB
    const size_t sz_feat = (size_t)B * T * 128 * 4;  // 128 MB
    const size_t sz_xpre = (size_t)B * T * 512 * 4;  // 512 MB

    const bool bigws = ws_size >= sz_xpre + sz_feat;

    float *y1, *y2, *feat, *xpre = nullptr;
    if (bigws) {
        xpre = (float*)ws;                 // 0 .. 512 MB (y1/y2 dead by then)
        y1   = (float*)ws;                 // 0 .. 32 MB
        y2   = (float*)(ws + sz_y1);       // 32 .. 96 MB
        feat = (float*)(ws + sz_xpre);     // 512 .. 640 MB
    } else {
        y1   = (float*)ws;
        y2   = (float*)(ws + sz_y1);
        feat = (float*)(ws + sz_y1 + sz_y2);
    }

    k_conv1<<<dim3(T / 256, B), 256, 0, stream>>>(x, c1w, bn1g, bn1b, bn1m, bn1v, y1, B, T);
    k_conv2<<<dim3(T / 256, B), 256, 0, stream>>>(y1, c2w, bn2g, bn2b, bn2m, bn2v, y2, B, T);
    k_conv3<<<dim3(T / 128, B), 256, 0, stream>>>(y2, c3w, bn3g, bn3b, bn3m, bn3v, feat, B, T);

    if (bigws) {
        k_proj<<<dim3(B * T / 64, 4), 256, 0, stream>>>(feat, w_ih, b_ih, b_hh, xpre);
        k_lstm<false><<<dim3(B), 512, 0, stream>>>(xpre, w_hh, w_ih, b_ih, b_hh, out, T);
    } else {
        k_lstm<true><<<dim3(B), 512, 0, stream>>>(feat, w_hh, w_ih, b_ih, b_hh, out, T);
    }
}

// Round 2
// 15932.220 us; speedup vs baseline: 1.5455x; 1.5455x over previous
//
#include <hip/hip_runtime.h>
#include <cstdint>
#include <cstddef>

#define BN_EPS 1e-5f

__device__ __forceinline__ float sigf(float x) {
    return 1.0f / (1.0f + __expf(-x));
}
__device__ __forceinline__ float tanhfast(float x) {
    return 2.0f / (1.0f + __expf(-2.0f * x)) - 1.0f;
}
__device__ __forceinline__ unsigned bfr(float x) {  // f32 -> bf16 bits (RNE)
    unsigned u = __float_as_uint(x);
    return (u + 0x7fffu + ((u >> 16) & 1u)) >> 16;
}

// ---------------- conv1 + BN + ReLU : x[B,T,9] -> y1[B,32,T] ----------------
__global__ __launch_bounds__(256) void k_conv1(
    const float* __restrict__ x, const float* __restrict__ w,
    const float* __restrict__ g, const float* __restrict__ bb,
    const float* __restrict__ m, const float* __restrict__ v,
    float* __restrict__ y1, int B, int T)
{
    const int TT = 256;
    __shared__ float xs[(TT + 6) * 9];
    const int b = blockIdx.y;
    const int t0 = blockIdx.x * TT;
    const int tid = threadIdx.x;

    for (int idx = tid; idx < (TT + 6) * 9; idx += 256) {
        int row = idx / 9, col = idx - row * 9;
        int tg = t0 - 3 + row;
        xs[idx] = (tg >= 0 && tg < T) ? x[((size_t)b * T + tg) * 9 + col] : 0.0f;
    }
    __syncthreads();

    float xv[63];
#pragma unroll
    for (int k = 0; k < 7; ++k)
#pragma unroll
        for (int ci = 0; ci < 9; ++ci)
            xv[k * 9 + ci] = xs[(tid + k) * 9 + ci];

    const int t = t0 + tid;
    for (int co = 0; co < 32; ++co) {
        float acc = 0.0f;
#pragma unroll
        for (int ci = 0; ci < 9; ++ci)
#pragma unroll
            for (int k = 0; k < 7; ++k)
                acc += xv[k * 9 + ci] * w[(co * 9 + ci) * 7 + k];
        float sc = g[co] / sqrtf(v[co] + BN_EPS);
        float bf = bb[co] - m[co] * sc;
        float o = acc * sc + bf;
        y1[((size_t)b * 32 + co) * T + t] = o > 0.0f ? o : 0.0f;
    }
}

// ---------------- conv2 + BN + ReLU : y1[B,32,T] -> y2[B,64,T] --------------
__global__ __launch_bounds__(256) void k_conv2(
    const float* __restrict__ y1, const float* __restrict__ w,
    const float* __restrict__ g, const float* __restrict__ bb,
    const float* __restrict__ m, const float* __restrict__ v,
    float* __restrict__ y2, int B, int T)
{
    const int TT = 256;
    __shared__ float ys[32 * (TT + 6)];
    const int b = blockIdx.y;
    const int t0 = blockIdx.x * TT;
    const int tid = threadIdx.x;

    for (int idx = tid; idx < 32 * (TT + 6); idx += 256) {
        int ci = idx / (TT + 6), i = idx - ci * (TT + 6);
        int tg = t0 - 3 + i;
        ys[idx] = (tg >= 0 && tg < T) ? y1[((size_t)b * 32 + ci) * T + tg] : 0.0f;
    }
    __syncthreads();

    float acc[64];
#pragma unroll
    for (int co = 0; co < 64; ++co) acc[co] = 0.0f;

    for (int ci = 0; ci < 32; ++ci) {
        float yw[7];
#pragma unroll
        for (int k = 0; k < 7; ++k) yw[k] = ys[ci * (TT + 6) + tid + k];
#pragma unroll
        for (int co = 0; co < 64; ++co)
#pragma unroll
            for (int k = 0; k < 7; ++k)
                acc[co] += yw[k] * w[(co * 32 + ci) * 7 + k];
    }

    const int t = t0 + tid;
    for (int co = 0; co < 64; ++co) {
        float sc = g[co] / sqrtf(v[co] + BN_EPS);
        float bf = bb[co] - m[co] * sc;
        float o = acc[co] * sc + bf;
        y2[((size_t)b * 64 + co) * T + t] = o > 0.0f ? o : 0.0f;
    }
}

// ------------- conv3 + BN + ReLU : y2[B,64,T] -> feat[B,T,128] --------------
__global__ __launch_bounds__(256) void k_conv3(
    const float* __restrict__ y2, const float* __restrict__ w,
    const float* __restrict__ g, const float* __restrict__ bb,
    const float* __restrict__ m, const float* __restrict__ v,
    float* __restrict__ feat, int B, int T)
{
    const int TT = 128;
    __shared__ float ys[64 * (TT + 6)];
    const int b = blockIdx.y;
    const int t0 = blockIdx.x * TT;
    const int tid = threadIdx.x;
    const int tl = tid & 127;
    const int half = __builtin_amdgcn_readfirstlane(tid >> 7);  // wave-uniform

    for (int idx = tid; idx < 64 * (TT + 6); idx += 256) {
        int ci = idx / (TT + 6), i = idx - ci * (TT + 6);
        int tg = t0 - 3 + i;
        ys[idx] = (tg >= 0 && tg < T) ? y2[((size_t)b * 64 + ci) * T + tg] : 0.0f;
    }
    __syncthreads();

    float acc[64];
#pragma unroll
    for (int q = 0; q < 64; ++q) acc[q] = 0.0f;

    for (int ci = 0; ci < 64; ++ci) {
        float yw[7];
#pragma unroll
        for (int k = 0; k < 7; ++k) yw[k] = ys[ci * (TT + 6) + tl + k];
#pragma unroll
        for (int q = 0; q < 64; ++q)
#pragma unroll
            for (int k = 0; k < 7; ++k)
                acc[q] += yw[k] * w[((half * 64 + q) * 64 + ci) * 7 + k];
    }

    const int t = t0 + tl;
    for (int q = 0; q < 64; ++q) {
        int co = half * 64 + q;
        float sc = g[co] / sqrtf(v[co] + BN_EPS);
        float bf = bb[co] - m[co] * sc;
        float o = acc[q] * sc + bf;
        feat[((size_t)b * T + t) * 128 + co] = o > 0.0f ? o : 0.0f;
    }
}

// --------------------------- reversed-time LSTM -----------------------------
// 512 threads = (j2 in [0,128)) x (k-quarter q in [0,4)).
// Thread (j2,q): partial dot over k in [32q,32q+32) for gates {j2+128g}.
// h-matvec in f32; x-matvec with bf16 weights (as before). Partials reduced
// through LDS; threads j<128 do the pointwise update.
__global__ __launch_bounds__(512, 2) void k_lstm2(
    const float* __restrict__ feat, const float* __restrict__ w_ih,
    const float* __restrict__ w_hh, const float* __restrict__ b_ih,
    const float* __restrict__ b_hh, float* __restrict__ out, int T)
{
    __shared__ __align__(16) float h_sh[128];
    __shared__ __align__(16) float x_sh[2][128];
    __shared__ float p_sh[16][128];  // [q*4+g][j2]

    const int b = blockIdx.x;
    const int tid = threadIdx.x;
    const int j2 = tid & 127;
    const int q = tid >> 7;  // wave-uniform (waves 2q, 2q+1)

    // --- load weights into registers ---
    float wh[4][32];          // W_hh[j2+128g][32q+kk], f32
    unsigned wiu[4][16];      // W_ih same slice, bf16 pairs packed
#pragma unroll
    for (int g = 0; g < 4; ++g) {
        const float* hr = w_hh + (size_t)(j2 + 128 * g) * 128 + 32 * q;
        const float* ir = w_ih + (size_t)(j2 + 128 * g) * 128 + 32 * q;
#pragma unroll
        for (int kk = 0; kk < 32; kk += 4) {
            float4 h4 = *reinterpret_cast<const float4*>(hr + kk);
            wh[g][kk + 0] = h4.x; wh[g][kk + 1] = h4.y;
            wh[g][kk + 2] = h4.z; wh[g][kk + 3] = h4.w;
            float4 i4 = *reinterpret_cast<const float4*>(ir + kk);
            wiu[g][kk / 2]     = (bfr(i4.y) << 16) | bfr(i4.x);
            wiu[g][kk / 2 + 1] = (bfr(i4.w) << 16) | bfr(i4.z);
        }
    }
    float bias[4];
#pragma unroll
    for (int g = 0; g < 4; ++g)
        bias[g] = b_ih[j2 + 128 * g] + b_hh[j2 + 128 * g];

    // --- init state, stage x for first two steps ---
    float cst = 0.0f;
    if (tid < 128) h_sh[tid] = 0.0f;
    float xnv = 0.0f;
    if (tid < 128) {
        x_sh[0][tid] = feat[((size_t)b * T + (T - 1)) * 128 + tid];
        if (T >= 2) xnv = feat[((size_t)b * T + (T - 2)) * 128 + tid];
    }
    __syncthreads();

    int cur = 0;
    for (int t = T - 1; t >= 0; --t) {
        // ---- phase 1: partial dots (all 512 threads) ----
        float a0 = 0.0f, a1 = 0.0f, a2 = 0.0f, a3 = 0.0f;
        const float4* hv = reinterpret_cast<const float4*>(h_sh) + 8 * q;
        const float4* xv = reinterpret_cast<const float4*>(x_sh[cur]) + 8 * q;
#pragma unroll
        for (int k4 = 0; k4 < 8; ++k4) {
            float4 h4 = hv[k4];
            float4 x4 = xv[k4];
#pragma unroll
            for (int g = 0; g < 4; ++g) {
                float* accp = (g == 0) ? &a0 : (g == 1) ? &a1 : (g == 2) ? &a2 : &a3;
                float a = *accp;
                a += h4.x * wh[g][4 * k4 + 0];
                a += h4.y * wh[g][4 * k4 + 1];
                a += h4.z * wh[g][4 * k4 + 2];
                a += h4.w * wh[g][4 * k4 + 3];
                unsigned u0 = wiu[g][2 * k4], u1 = wiu[g][2 * k4 + 1];
                a += x4.x * __uint_as_float(u0 << 16);
                a += x4.y * __uint_as_float(u0 & 0xffff0000u);
                a += x4.z * __uint_as_float(u1 << 16);
                a += x4.w * __uint_as_float(u1 & 0xffff0000u);
                *accp = a;
            }
        }
        p_sh[q * 4 + 0][j2] = a0;
        p_sh[q * 4 + 1][j2] = a1;
        p_sh[q * 4 + 2][j2] = a2;
        p_sh[q * 4 + 3][j2] = a3;
        __syncthreads();  // A: partials visible

        // ---- phase 2: reduce + pointwise (threads j<128) ----
        if (tid < 128) {
            float gi = bias[0] + ((p_sh[0][tid] + p_sh[4][tid]) + (p_sh[8][tid]  + p_sh[12][tid]));
            float gf = bias[1] + ((p_sh[1][tid] + p_sh[5][tid]) + (p_sh[9][tid]  + p_sh[13][tid]));
            float gg = bias[2] + ((p_sh[2][tid] + p_sh[6][tid]) + (p_sh[10][tid] + p_sh[14][tid]));
            float go = bias[3] + ((p_sh[3][tid] + p_sh[7][tid]) + (p_sh[11][tid] + p_sh[15][tid]));
            cst = sigf(gf) * cst + sigf(gi) * tanhfast(gg);
            float h = sigf(go) * tanhfast(cst);
            h_sh[tid] = h;
            out[((size_t)b * T + t) * 128 + tid] = h;
            x_sh[cur ^ 1][tid] = xnv;  // x for step t-1
            xnv = (t >= 2) ? feat[((size_t)b * T + (t - 2)) * 128 + tid] : 0.0f;
        }
        cur ^= 1;
        __syncthreads();  // B: h_sh / x_sh ready for next step
    }
}

extern "C" void kernel_launch(void* const* d_in, const int* in_sizes, int n_in,
                              void* d_out, int out_size, void* d_ws, size_t ws_size,
                              hipStream_t stream)
{
    const float* x    = (const float*)d_in[0];
    const float* c1w  = (const float*)d_in[1];
    const float* bn1g = (const float*)d_in[2];
    const float* bn1b = (const float*)d_in[3];
    const float* bn1m = (const float*)d_in[4];
    const float* bn1v = (const float*)d_in[5];
    const float* c2w  = (const float*)d_in[6];
    const float* bn2g = (const float*)d_in[7];
    const float* bn2b = (const float*)d_in[8];
    const float* bn2m = (const float*)d_in[9];
    const float* bn2v = (const float*)d_in[10];
    const float* c3w  = (const float*)d_in[11];
    const float* bn3g = (const float*)d_in[12];
    const float* bn3b = (const float*)d_in[13];
    const float* bn3m = (const float*)d_in[14];
    const float* bn3v = (const float*)d_in[15];
    const float* w_ih = (const float*)d_in[16];
    const float* w_hh = (const float*)d_in[17];
    const float* b_ih = (const float*)d_in[18];
    const float* b_hh = (const float*)d_in[19];
    float* out = (float*)d_out;

    const int B = 64, T = 4096;
    char* ws = (char*)d_ws;
    const size_t sz_y1 = (size_t)B * 32 * T * 4;   // 32 MB
    const size_t sz_y2 = (size_t)B * 64 * T * 4;   // 64 MB

    float* y1   = (float*)ws;
    float* y2   = (float*)(ws + sz_y1);
    float* feat = (float*)(ws + sz_y1 + sz_y2);

    k_conv1<<<dim3(T / 256, B), 256, 0, stream>>>(x, c1w, bn1g, bn1b, bn1m, bn1v, y1, B, T);
    k_conv2<<<dim3(T / 256, B), 256, 0, stream>>>(y1, c2w, bn2g, bn2b, bn2m, bn2v, y2, B, T);
    k_conv3<<<dim3(T / 128, B), 256, 0, stream>>>(y2, c3w, bn3g, bn3b, bn3m, bn3v, feat, B, T);

    k_lstm2<<<dim3(B), 512, 0, stream>>>(feat, w_ih, w_hh, b_ih, b_hh, out, T);
}